// Round 17
// baseline (213.337 us; speedup 1.0000x reference)
//
#include <hip/hip_runtime.h>
#include <hip/hip_bf16.h>

#define BB 2
#define SS 2048
#define INC 64
#define HIDN 512
#define NHH 8
#define HDD 64
#define SP 2054   // padded seq rows per batch (3 zero + 2048 + 3 zero)

typedef __attribute__((ext_vector_type(8))) short bf16x8;
typedef __attribute__((ext_vector_type(4))) float f32x4;

__device__ __forceinline__ short f2bf(float f) {
  union { __hip_bfloat16 h; short s; } u;
  u.h = __float2bfloat16(f);
  return u.s;
}
__device__ __forceinline__ float bf2f(short s) {
  return __uint_as_float(((unsigned)(unsigned short)s) << 16);
}

// Fragment layouts:
//  B-operand of [N][K]: (n>>6)*(K/32*2048) + (k>>5)*2048 + ((n&63)>>4)*512
//                       + (((k&31)>>3)*16+(n&15))*8 + (k&7)
//  A-operand of [M][K=512]: (m>>4)*8192 + (k>>5)*512
//                       + (((k&31)>>3)*16+(m&15))*8 + (k&7)

// ---------------------------------------------------------------------------
// prep (slim): conv-critical packing + small tensors.
// ---------------------------------------------------------------------------
__global__ __launch_bounds__(256) void prep_kernel(
    const float* __restrict__ x, const float* __restrict__ w1,
    const float* __restrict__ b1, const float* __restrict__ w2,
    const float* __restrict__ b2, const float* __restrict__ w3,
    const float* __restrict__ b3, const float* __restrict__ bq,
    const float* __restrict__ bk_, const float* __restrict__ bv_,
    const float* __restrict__ Wkp, const float* __restrict__ Wvp,
    const float* __restrict__ bvp, float* __restrict__ ball,
    short* __restrict__ Wkpbf, short* __restrict__ W2bf,
    float* __restrict__ cvec, short* __restrict__ xbfp,
    short* __restrict__ Wcbf, float* __restrict__ bcat) {
  int i0 = blockIdx.x * 256 + threadIdx.x;
  int stride = gridDim.x * 256;
  for (int g = i0; g < BB * SP * 8; g += stride) {
    int row = g >> 3, c0 = (g & 7) << 3;
    int b = row / SP, pr = row - b * SP;
    int sg = pr - 3;
    bf16x8 v;
    if (sg >= 0 && sg < SS) {
      const float* src = x + ((size_t)(b * SS + sg) << 6) + c0;
      float4 f0 = *(const float4*)src;
      float4 f1 = *(const float4*)(src + 4);
      v[0] = f2bf(f0.x); v[1] = f2bf(f0.y); v[2] = f2bf(f0.z); v[3] = f2bf(f0.w);
      v[4] = f2bf(f1.x); v[5] = f2bf(f1.y); v[6] = f2bf(f1.z); v[7] = f2bf(f1.w);
    } else {
#pragma unroll
      for (int e = 0; e < 8; e++) v[e] = 0;
    }
    *(bf16x8*)(xbfp + ((size_t)row << 6) + c0) = v;
  }
  for (int g = i0; g < 28672; g += stride) {
    int c = g / 56;
    int rem = g - c * 56;
    int k = rem << 3;
    int t = k >> 6;
    int ci0 = k & 63;
    bf16x8 v;
#pragma unroll
    for (int e = 0; e < 8; e++) {
      int ci = ci0 + e;
      float val = 0.f;
      if (c < 171) {
        int kk = t - 2;
        if (kk >= 0 && kk < 3) val = w1[(c * 64 + ci) * 3 + kk];
      } else if (c < 342) {
        int kk = t - 1;
        if (kk >= 0 && kk < 5) val = w2[((c - 171) * 64 + ci) * 5 + kk];
      } else {
        val = w3[((c - 342) * 64 + ci) * 7 + t];
      }
      v[e] = f2bf(val);
    }
    size_t off = (size_t)(c >> 6) * 28672 + (size_t)(k >> 5) * 2048 +
                 (size_t)((c & 63) >> 4) * 512 +
                 ((((k & 31) >> 3) * 16 + (c & 15)) << 3);
    *(bf16x8*)(Wcbf + off) = v;
  }
  for (int idx = i0; idx < 4096; idx += stride) {
    Wkpbf[idx] = f2bf(Wkp[idx]);
    int j = idx >> 6, d = idx & 63;
    float s = 0.f;
#pragma unroll 8
    for (int i = 0; i < 64; i++) s += Wvp[j * 64 + i] * Wvp[i * 64 + d];
    W2bf[idx] = f2bf(s);
  }
  if (i0 < 1536) {
    float v;
    if (i0 < 512)       v = bq[i0];
    else if (i0 < 1024) v = bk_[i0 - 512];
    else                v = bv_[i0 - 1024];
    ball[i0] = v;
  }
  if (i0 < 512) {
    float v;
    if (i0 < 171)      v = b1[i0];
    else if (i0 < 342) v = b2[i0 - 171];
    else               v = b3[i0 - 342];
    bcat[i0] = v;
  }
  if (i0 < 64) {
    float s = bvp[i0];
#pragma unroll 8
    for (int i = 0; i < 64; i++) s += bvp[i] * Wvp[i0 * 64 + i];
    cvec[i0] = s;
  }
}

// ---------------------------------------------------------------------------
// conv GEMM + Wall/Wo frag-packing fused. blocks [0,256): conv (dual-write
// h). blocks [256,768): Wall/Wo frag-pack (consumed later; overlapped).
// ---------------------------------------------------------------------------
__global__ __launch_bounds__(256, 4) void gemm_conv_fused(
    const short* __restrict__ xbfp, const short* __restrict__ Wcbf,
    const float* __restrict__ bcat, short* __restrict__ hbf,
    short* __restrict__ hAf, const float* __restrict__ Wq,
    const float* __restrict__ Wk_, const float* __restrict__ Wv_,
    const float* __restrict__ Wo, short* __restrict__ Wallbf,
    short* __restrict__ Wobf) {
  int blk = blockIdx.x;
  int tid = threadIdx.x;
  if (blk >= 256) {
    int i0 = (blk - 256) * 256 + tid;
    if (i0 < 98304) {
      int n = i0 >> 6;
      int k = (i0 & 63) << 3;
      const float* src;
      if (n < 512)       src = Wq  + (size_t)n * 512 + k;
      else if (n < 1024) src = Wk_ + (size_t)(n - 512) * 512 + k;
      else               src = Wv_ + (size_t)(n - 1024) * 512 + k;
      float4 f0 = *(const float4*)src;
      float4 f1 = *(const float4*)(src + 4);
      bf16x8 v;
      v[0] = f2bf(f0.x); v[1] = f2bf(f0.y); v[2] = f2bf(f0.z); v[3] = f2bf(f0.w);
      v[4] = f2bf(f1.x); v[5] = f2bf(f1.y); v[6] = f2bf(f1.z); v[7] = f2bf(f1.w);
      size_t off = (size_t)(n >> 6) * 32768 + (size_t)(k >> 5) * 2048 +
                   (size_t)((n & 63) >> 4) * 512 +
                   ((((k & 31) >> 3) * 16 + (n & 15)) << 3);
      *(bf16x8*)(Wallbf + off) = v;
    } else {
      int g = i0 - 98304;
      int n = g >> 6;
      int k = (g & 63) << 3;
      const float* src = Wo + (size_t)n * 512 + k;
      float4 f0 = *(const float4*)src;
      float4 f1 = *(const float4*)(src + 4);
      bf16x8 v;
      v[0] = f2bf(f0.x); v[1] = f2bf(f0.y); v[2] = f2bf(f0.z); v[3] = f2bf(f0.w);
      v[4] = f2bf(f1.x); v[5] = f2bf(f1.y); v[6] = f2bf(f1.z); v[7] = f2bf(f1.w);
      size_t off = (size_t)(n >> 6) * 32768 + (size_t)(k >> 5) * 2048 +
                   (size_t)((n & 63) >> 4) * 512 +
                   ((((k & 31) >> 3) * 16 + (n & 15)) << 3);
      *(bf16x8*)(Wobf + off) = v;
    }
    return;
  }
  int m0 = (blk >> 3) * 128;
  int n0 = (blk & 7) * 64;
  int wvv = tid >> 6, lane = tid & 63;
  int quad = lane >> 4, l16 = lane & 15;
  int mw = m0 + wvv * 32;
  int r0 = mw + l16, r1 = r0 + 16;
  int b0 = r0 >> 11, s0 = r0 & 2047;
  int b1 = r1 >> 11, s1 = r1 & 2047;
  const short* ap0 = xbfp + (size_t)(b0 * SP + s0) * 64 + quad * 8;
  const short* ap1 = xbfp + (size_t)(b1 * SP + s1) * 64 + quad * 8;
  const short* bp = Wcbf + (size_t)(n0 >> 6) * 28672 + lane * 8;
  f32x4 acc[2][4] = {};
  bf16x8 cA0 = *(const bf16x8*)ap0;
  bf16x8 cA1 = *(const bf16x8*)ap1;
  bf16x8 cB0 = *(const bf16x8*)(bp + 0 * 512);
  bf16x8 cB1 = *(const bf16x8*)(bp + 1 * 512);
  bf16x8 cB2 = *(const bf16x8*)(bp + 2 * 512);
  bf16x8 cB3 = *(const bf16x8*)(bp + 3 * 512);
#pragma unroll 2
  for (int ks = 0; ks < 14; ks++) {
    int kn = (ks + 1 < 14 ? ks + 1 : 13);
    int offa = kn * 32;
    int offb = kn * 2048;
    bf16x8 nA0 = *(const bf16x8*)(ap0 + offa);
    bf16x8 nA1 = *(const bf16x8*)(ap1 + offa);
    bf16x8 nB0 = *(const bf16x8*)(bp + offb + 0 * 512);
    bf16x8 nB1 = *(const bf16x8*)(bp + offb + 1 * 512);
    bf16x8 nB2 = *(const bf16x8*)(bp + offb + 2 * 512);
    bf16x8 nB3 = *(const bf16x8*)(bp + offb + 3 * 512);
    acc[0][0] = __builtin_amdgcn_mfma_f32_16x16x32_bf16(cA0, cB0, acc[0][0], 0, 0, 0);
    acc[1][0] = __builtin_amdgcn_mfma_f32_16x16x32_bf16(cA1, cB0, acc[1][0], 0, 0, 0);
    acc[0][1] = __builtin_amdgcn_mfma_f32_16x16x32_bf16(cA0, cB1, acc[0][1], 0, 0, 0);
    acc[1][1] = __builtin_amdgcn_mfma_f32_16x16x32_bf16(cA1, cB1, acc[1][1], 0, 0, 0);
    acc[0][2] = __builtin_amdgcn_mfma_f32_16x16x32_bf16(cA0, cB2, acc[0][2], 0, 0, 0);
    acc[1][2] = __builtin_amdgcn_mfma_f32_16x16x32_bf16(cA1, cB2, acc[1][2], 0, 0, 0);
    acc[0][3] = __builtin_amdgcn_mfma_f32_16x16x32_bf16(cA0, cB3, acc[0][3], 0, 0, 0);
    acc[1][3] = __builtin_amdgcn_mfma_f32_16x16x32_bf16(cA1, cB3, acc[1][3], 0, 0, 0);
    cA0 = nA0; cA1 = nA1;
    cB0 = nB0; cB1 = nB1; cB2 = nB2; cB3 = nB3;
  }
#pragma unroll
  for (int mt = 0; mt < 2; mt++) {
#pragma unroll
    for (int r = 0; r < 4; r++) {
      int m = mw + mt * 16 + quad * 4 + r;
      size_t abase = (size_t)(m >> 4) * 8192;
      int m15 = m & 15;
#pragma unroll
      for (int t = 0; t < 4; t++) {
        int n = n0 + t * 16 + l16;
        float v = fmaxf(acc[mt][t][r] + bcat[n], 0.f);
        short val = f2bf(v);
        hbf[(size_t)m * 512 + n] = val;
        hAf[abase + (size_t)(n >> 5) * 512 +
            ((((n & 31) >> 3) * 16 + m15) << 3) + (n & 7)] = val;
      }
    }
  }
}

// ---------------------------------------------------------------------------
// MFMA QKV gemm. A from frag-packed hAf; B frag-packed.
// ---------------------------------------------------------------------------
__global__ __launch_bounds__(256, 4) void gemm_qkv(
    const short* __restrict__ hAf, const short* __restrict__ Wbf,
    const float* __restrict__ bias, short* __restrict__ Qh,
    short* __restrict__ Kh, short* __restrict__ Vh) {
  int m0 = blockIdx.x * 128;
  int n0 = blockIdx.y * 64;
  int tid = threadIdx.x;
  int wvv = tid >> 6, lane = tid & 63;
  int quad = lane >> 4, l16 = lane & 15;
  int mw = m0 + wvv * 32;
  const short* ap0 = hAf + (size_t)(mw >> 4) * 8192 + lane * 8;
  const short* ap1 = ap0 + 8192;
  const short* bp = Wbf + (size_t)(n0 >> 6) * 32768 + lane * 8;
  f32x4 acc[2][4] = {};
  bf16x8 cA0 = *(const bf16x8*)ap0;
  bf16x8 cA1 = *(const bf16x8*)ap1;
  bf16x8 cB0 = *(const bf16x8*)(bp + 0 * 512);
  bf16x8 cB1 = *(const bf16x8*)(bp + 1 * 512);
  bf16x8 cB2 = *(const bf16x8*)(bp + 2 * 512);
  bf16x8 cB3 = *(const bf16x8*)(bp + 3 * 512);
#pragma unroll 2
  for (int ks = 0; ks < 16; ks++) {
    int kn = (ks + 1 < 16 ? ks + 1 : 15);
    int offab = kn * 512;
    int offb = kn * 2048;
    bf16x8 nA0 = *(const bf16x8*)(ap0 + offab);
    bf16x8 nA1 = *(const bf16x8*)(ap1 + offab);
    bf16x8 nB0 = *(const bf16x8*)(bp + offb + 0 * 512);
    bf16x8 nB1 = *(const bf16x8*)(bp + offb + 1 * 512);
    bf16x8 nB2 = *(const bf16x8*)(bp + offb + 2 * 512);
    bf16x8 nB3 = *(const bf16x8*)(bp + offb + 3 * 512);
    acc[0][0] = __builtin_amdgcn_mfma_f32_16x16x32_bf16(cA0, cB0, acc[0][0], 0, 0, 0);
    acc[1][0] = __builtin_amdgcn_mfma_f32_16x16x32_bf16(cA1, cB0, acc[1][0], 0, 0, 0);
    acc[0][1] = __builtin_amdgcn_mfma_f32_16x16x32_bf16(cA0, cB1, acc[0][1], 0, 0, 0);
    acc[1][1] = __builtin_amdgcn_mfma_f32_16x16x32_bf16(cA1, cB1, acc[1][1], 0, 0, 0);
    acc[0][2] = __builtin_amdgcn_mfma_f32_16x16x32_bf16(cA0, cB2, acc[0][2], 0, 0, 0);
    acc[1][2] = __builtin_amdgcn_mfma_f32_16x16x32_bf16(cA1, cB2, acc[1][2], 0, 0, 0);
    acc[0][3] = __builtin_amdgcn_mfma_f32_16x16x32_bf16(cA0, cB3, acc[0][3], 0, 0, 0);
    acc[1][3] = __builtin_amdgcn_mfma_f32_16x16x32_bf16(cA1, cB3, acc[1][3], 0, 0, 0);
    cA0 = nA0; cA1 = nA1;
    cB0 = nB0; cB1 = nB1; cB2 = nB2; cB3 = nB3;
  }
  int which = n0 >> 9;
  int head = (n0 >> 6) & 7;
  short* dst = which == 0 ? Qh : (which == 1 ? Kh : Vh);
  float scale = which == 0 ? 0.125f : 1.0f;
#pragma unroll
  for (int mt = 0; mt < 2; mt++) {
#pragma unroll
    for (int r = 0; r < 4; r++) {
      int m = mw + mt * 16 + quad * 4 + r;
      int bb = m >> 11, s = m & 2047;
      size_t rowoff = ((size_t)(bb * 8 + head) * 2048 + s) * 64;
#pragma unroll
      for (int t = 0; t < 4; t++) {
        int hd = t * 16 + l16;
        float v = acc[mt][t][r] + bias[n0 + hd];
        dst[rowoff + hd] = f2bf(v * scale);
      }
    }
  }
}

// ---------------------------------------------------------------------------
// kpvp (standalone, 256 blocks): Kfrag = frag-packed K@Wkp.T+bkp; Vpp.
// ---------------------------------------------------------------------------
__global__ __launch_bounds__(256, 4) void kpvp_kernel(
    const short* __restrict__ Kh, const short* __restrict__ Vh,
    const short* __restrict__ Wkpbf, const float* __restrict__ bkp,
    const short* __restrict__ W2bf, const float* __restrict__ cvec,
    short* __restrict__ Kfrag, float* __restrict__ Vpp) {
  int tid = threadIdx.x;
  int m0 = blockIdx.x * 128;
  int wvv = tid >> 6, lane = tid & 63;
  int quad = lane >> 4, l16 = lane & 15;
  int mw = m0 + wvv * 32;
  {
    const short* ap0 = Kh + (size_t)(mw + l16) * 64 + quad * 8;
    const short* ap1 = ap0 + 16 * 64;
    const short* bp = Wkpbf + l16 * 64 + quad * 8;
    bf16x8 A00 = *(const bf16x8*)ap0, A01 = *(const bf16x8*)(ap0 + 32);
    bf16x8 A10 = *(const bf16x8*)ap1, A11 = *(const bf16x8*)(ap1 + 32);
    f32x4 acc[2][4] = {};
#pragma unroll
    for (int t = 0; t < 4; t++) {
      bf16x8 B0 = *(const bf16x8*)(bp + t * 16 * 64);
      bf16x8 B1 = *(const bf16x8*)(bp + t * 16 * 64 + 32);
      acc[0][t] = __builtin_amdgcn_mfma_f32_16x16x32_bf16(A00, B0, acc[0][t], 0, 0, 0);
      acc[0][t] = __builtin_amdgcn_mfma_f32_16x16x32_bf16(A01, B1, acc[0][t], 0, 0, 0);
      acc[1][t] = __builtin_amdgcn_mfma_f32_16x16x32_bf16(A10, B0, acc[1][t], 0, 0, 0);
      acc[1][t] = __builtin_amdgcn_mfma_f32_16x16x32_bf16(A11, B1, acc[1][t], 0, 0, 0);
    }
#pragma unroll
    for (int mt = 0; mt < 2; mt++)
#pragma unroll
      for (int r = 0; r < 4; r++) {
        int m = mw + mt * 16 + quad * 4 + r;
        int m15 = m & 15;
        size_t gbase = (size_t)(m >> 4) * 1024;
#pragma unroll
        for (int t = 0; t < 4; t++) {
          int n = t * 16 + l16;
          short val = f2bf(acc[mt][t][r] + bkp[n]);
          Kfrag[gbase + (size_t)(n >> 5) * 512 +
                ((((n & 31) >> 3) * 16 + m15) << 3) + (n & 7)] = val;
        }
      }
  }
  {
    const short* ap0 = Vh + (size_t)(mw + l16) * 64 + quad * 8;
    const short* ap1 = ap0 + 16 * 64;
    const short* bp = W2bf + l16 * 64 + quad * 8;
    bf16x8 A00 = *(const bf16x8*)ap0, A01 = *(const bf16x8*)(ap0 + 32);
    bf16x8 A10 = *(const bf16x8*)ap1, A11 = *(const bf16x8*)(ap1 + 32);
    f32x4 acc[2][4] = {};
#pragma unroll
    for (int t = 0; t < 4; t++) {
      bf16x8 B0 = *(const bf16x8*)(bp + t * 16 * 64);
      bf16x8 B1 = *(const bf16x8*)(bp + t * 16 * 64 + 32);
      acc[0][t] = __builtin_amdgcn_mfma_f32_16x16x32_bf16(A00, B0, acc[0][t], 0, 0, 0);
      acc[0][t] = __builtin_amdgcn_mfma_f32_16x16x32_bf16(A01, B1, acc[0][t], 0, 0, 0);
      acc[1][t] = __builtin_amdgcn_mfma_f32_16x16x32_bf16(A10, B0, acc[1][t], 0, 0, 0);
      acc[1][t] = __builtin_amdgcn_mfma_f32_16x16x32_bf16(A11, B1, acc[1][t], 0, 0, 0);
    }
#pragma unroll
    for (int mt = 0; mt < 2; mt++)
#pragma unroll
      for (int r = 0; r < 4; r++) {
        int m = mw + mt * 16 + quad * 4 + r;
#pragma unroll
        for (int t = 0; t < 4; t++) {
          int n = t * 16 + l16;
          Vpp[(size_t)m * 64 + n] = acc[mt][t][r] + cvec[n];
        }
      }
  }
}

// ---------------------------------------------------------------------------
// global sparse attention + local windowed attention MERGED (v17).
// Both halves write 0.5*result as BF16 in A-layout (fp32 was the r16 tax:
// +12MB writes + double-width reads in the epilogue).
// blocks [0,1024): global scan (v12 core) -> spA (bf16).
// blocks [1024,1536): local windowed attn -> ctxlA (bf16).
// ---------------------------------------------------------------------------
__global__ __launch_bounds__(256, 4) void global_local_kernel(
    const short* __restrict__ Qh, const short* __restrict__ Kfrag,
    const float* __restrict__ Vpp, const short* __restrict__ Kh,
    const short* __restrict__ Vh, short* __restrict__ spA,
    short* __restrict__ ctxlA) {
  int tid = threadIdx.x;
  int wv = tid >> 6;
  int lane = tid & 63;
  int quad = lane >> 4, l16 = lane & 15;

  __shared__ unsigned swl[4][16][17];
  __shared__ float twl[2][16][17];
  __shared__ int   txl[2][16][17];
  __shared__ float Sloc[4][2][16][17];
  __shared__ float wloc[4][16][8];

  if (blockIdx.x >= 1024) {
    // ---- local windowed attention ----
    int tile = (blockIdx.x - 1024) * 4 + wv;   // 0..2047
    int bh = tile >> 7;
    int q0 = (tile & 127) * 16;

    const short* qbase = Qh + (size_t)(bh * 2048 + q0 + l16) * 64 + quad * 8;
    bf16x8 a0 = *(const bf16x8*)qbase;
    bf16x8 a1 = *(const bf16x8*)(qbase + 32);

    int k0a = min(max(q0 - 2 + l16, 0), 2047);
    int k1a = min(q0 + 6 + l16, 2047);
    const short* kb0 = Kh + (size_t)(bh * 2048 + k0a) * 64 + quad * 8;
    const short* kb1 = Kh + (size_t)(bh * 2048 + k1a) * 64 + quad * 8;
    bf16x8 B00 = *(const bf16x8*)kb0;
    bf16x8 B01 = *(const bf16x8*)(kb0 + 32);
    bf16x8 B10 = *(const bf16x8*)kb1;
    bf16x8 B11 = *(const bf16x8*)(kb1 + 32);
    f32x4 C0 = {0.f, 0.f, 0.f, 0.f};
    f32x4 C1 = {0.f, 0.f, 0.f, 0.f};
    C0 = __builtin_amdgcn_mfma_f32_16x16x32_bf16(a0, B00, C0, 0, 0, 0);
    C0 = __builtin_amdgcn_mfma_f32_16x16x32_bf16(a1, B01, C0, 0, 0, 0);
    C1 = __builtin_amdgcn_mfma_f32_16x16x32_bf16(a0, B10, C1, 0, 0, 0);
    C1 = __builtin_amdgcn_mfma_f32_16x16x32_bf16(a1, B11, C1, 0, 0, 0);
#pragma unroll
    for (int r = 0; r < 4; r++) {
      Sloc[wv][0][quad * 4 + r][l16] = C0[r];
      Sloc[wv][1][quad * 4 + r][l16] = C1[r];
    }
    __builtin_amdgcn_wave_barrier();
    if (lane < 16) {
      int q = lane;
      float sc[5];
      bool ok[5];
#pragma unroll
      for (int j = 0; j < 5; j++) {
        int offq = q + j - 2;
        int sg = q0 + offq;
        ok[j] = (sg >= 0 && sg < SS);
        int t = offq <= 13 ? 0 : 1;
        int col = t ? offq - 6 : offq + 2;
        sc[j] = ok[j] ? Sloc[wv][t][q][col] : -3.0e38f;
      }
      float m = -3.0e38f;
#pragma unroll
      for (int j = 0; j < 5; j++) m = fmaxf(m, sc[j]);
      float e[5], l = 0.f;
#pragma unroll
      for (int j = 0; j < 5; j++) {
        e[j] = ok[j] ? __expf(sc[j] - m) : 0.f;
        l += e[j];
      }
      float inv = 1.f / l;
#pragma unroll
      for (int j = 0; j < 5; j++) wloc[wv][q][j] = e[j] * inv;
    }
    __builtin_amdgcn_wave_barrier();
    {
      int q = lane >> 2, jb = (lane & 3) * 16;
      int s = q0 + q;
      float acc[16] = {};
#pragma unroll
      for (int j = 0; j < 5; j++) {
        int sg = s + j - 2;
        if (sg >= 0 && sg < SS) {
          float w = wloc[wv][q][j];
          const short* vr = Vh + (size_t)(bh * 2048 + sg) * 64 + jb;
#pragma unroll
          for (int u = 0; u < 16; u += 4) {
            short4 v4 = *(const short4*)(vr + u);
            acc[u + 0] += w * bf2f(v4.x);
            acc[u + 1] += w * bf2f(v4.y);
            acc[u + 2] += w * bf2f(v4.z);
            acc[u + 3] += w * bf2f(v4.w);
          }
        }
      }
      // write 0.5*ctxl as bf16 in A-layout (M = b*2048+s, k = hh*64+jb+u)
      int b = bh >> 3, hh = bh & 7;
      int M = b * 2048 + s;
      int m15 = M & 15;
      size_t mbase = (size_t)(M >> 4) * 8192;
#pragma unroll
      for (int u = 0; u < 16; u += 8) {
        int k0 = hh * 64 + jb + u;
        size_t off = mbase + (size_t)(k0 >> 5) * 512 +
                     ((((k0 & 31) >> 3) * 16 + m15) << 3);
        bf16x8 v;
#pragma unroll
        for (int e = 0; e < 8; e++) v[e] = f2bf(0.5f * acc[u + e]);
        *(bf16x8*)(ctxlA + off) = v;
      }
    }
    return;
  }

  // ---- global sparse attention (v12 core) ----
  int tb = wv >> 1;
  int half = wv & 1;
  int p = blockIdx.x;
  int bh = (p & 7) * 2 + ((p >> 3) & 1);
  int seg = p >> 4;
  int tile = seg * 2 + tb;
  int q0 = tile * 16;

  const short* qbase = Qh + (size_t)(bh * 2048 + q0 + l16) * 64 + quad * 8;
  bf16x8 a0 = *(const bf16x8*)qbase;
  bf16x8 a1 = *(const bf16x8*)(qbase + 32);

  const short* kf =
      Kfrag + (size_t)bh * (128 * 1024) + (size_t)half * (64 * 1024) + lane * 8;

  unsigned er[4][8];
#pragma unroll
  for (int a = 0; a < 4; a++)
#pragma unroll
    for (int j = 0; j < 8; j++) er[a][j] = 0u;

  auto insert8 = [&](unsigned (&e)[8], unsigned cand) {
    unsigned n0, n1, n2, n3, n4, n5, n6, n7;
    asm("v_max_u32 %0, %1, %2" : "=v"(n0) : "v"(e[0]), "v"(cand));
    asm("v_med3_u32 %0, %1, %2, %3" : "=v"(n1) : "v"(e[0]), "v"(e[1]), "v"(cand));
    asm("v_med3_u32 %0, %1, %2, %3" : "=v"(n2) : "v"(e[1]), "v"(e[2]), "v"(cand));
    asm("v_med3_u32 %0, %1, %2, %3" : "=v"(n3) : "v"(e[2]), "v"(e[3]), "v"(cand));
    asm("v_med3_u32 %0, %1, %2, %3" : "=v"(n4) : "v"(e[3]), "v"(e[4]), "v"(cand));
    asm("v_med3_u32 %0, %1, %2, %3" : "=v"(n5) : "v"(e[4]), "v"(e[5]), "v"(cand));
    asm("v_med3_u32 %0, %1, %2, %3" : "=v"(n6) : "v"(e[5]), "v"(e[6]), "v"(cand));
    asm("v_med3_u32 %0, %1, %2, %3" : "=v"(n7) : "v"(e[6]), "v"(e[7]), "v"(cand));
    e[0] = n0; e[1] = n1; e[2] = n2; e[3] = n3;
    e[4] = n4; e[5] = n5; e[6] = n6; e[7] = n7;
  };
  auto mkcand = [&](float s, int idxr) -> unsigned {
    unsigned u = __float_as_uint(s);
    u ^= ((unsigned)((int)u >> 31)) | 0x80000000u;
    return (u & 0xFFFFF800u) | (unsigned)idxr;
  };

  int idxb = 2047 - half * 1024 - l16;
#pragma unroll 4
  for (int g = 0; g < 64; g++) {
    bf16x8 B00 = *(const bf16x8*)(kf + g * 1024);
    bf16x8 B01 = *(const bf16x8*)(kf + g * 1024 + 512);
    f32x4 C0 = {0.f, 0.f, 0.f, 0.f};
    C0 = __builtin_amdgcn_mfma_f32_16x16x32_bf16(a0, B00, C0, 0, 0, 0);
    C0 = __builtin_amdgcn_mfma_f32_16x16x32_bf16(a1, B01, C0, 0, 0, 0);
    int idxr = idxb - (g << 4);
    insert8(er[0], mkcand(C0[0], idxr));
    insert8(er[1], mkcand(C0[1], idxr));
    insert8(er[2], mkcand(C0[2], idxr));
    insert8(er[3], mkcand(C0[3], idxr));
  }

  {
    unsigned sw[4] = {0u, 0u, 0u, 0u};
#pragma unroll
    for (int t = 0; t < 16; t++) {
#pragma unroll
      for (int a = 0; a < 4; a++) {
        unsigned w = er[a][0];
#pragma unroll
        for (int mm = 1; mm <= 8; mm <<= 1) {
          unsigned o = (unsigned)__shfl_xor((int)w, mm);
          w = w > o ? w : o;
        }
        bool pop = (er[a][0] == w);
#pragma unroll
        for (int j = 0; j < 7; j++) er[a][j] = pop ? er[a][j + 1] : er[a][j];
        er[a][7] = pop ? 0u : er[a][7];
        if (l16 == t) sw[a] = w;
      }
    }
#pragma unroll
    for (int a = 0; a < 4; a++) swl[wv][quad * 4 + a][l16] = sw[a];
  }
  __syncthreads();

  if (tid < 32) {
    int tb2 = tid >> 4, q = tid & 15;
    const unsigned* A = swl[tb2 * 2][q];
    const unsigned* Bv = swl[tb2 * 2 + 1][q];
    auto decode = [&](unsigned w) -> float {
      unsigned wb = w & 0xFFFFF800u;
      unsigned uu = (w & 0x80000000u) ? (wb ^ 0x80000000u) : ~wb;
      return (w == 0u) ? -1.0e30f : __uint_as_float(uu);
    };
    unsigned h0 = A[0], h1 = Bv[0];
    float mval = decode(h0 > h1 ? h0 : h1);
    float lsum = 0.f;
    float ev[16];
    int ki[16];
#pragma unroll
    for (int i = 0; i < 16; i++) {
      unsigned wa = A[i], wb2 = Bv[15 - i];
      unsigned w = wa > wb2 ? wa : wb2;
      float sv = decode(w);
      float ex = __expf(sv - mval);
      lsum += ex;
      ev[i] = ex;
      ki[i] = 2047 - (int)(w & 0x7FFu);
    }
    float inv = 1.f / lsum;
#pragma unroll
    for (int i = 0; i < 16; i++) {
      twl[tb2][q][i] = ev[i] * inv;
      txl[tb2][q][i] = ki[i];
    }
  }
  __syncthreads();

  {
    int tb2 = tid >> 7;
    int r = tid & 127;
    int q = r >> 3, d0 = (r & 7) * 8;
    int tile2 = seg * 2 + tb2;
    int q02 = tile2 * 16;
    int b = bh >> 3, hh = bh & 7;
    const float* vball = Vpp + (size_t)bh * (2048 * 64) + d0;
    float acc[8];
#pragma unroll
    for (int u = 0; u < 8; u++) acc[u] = 0.f;
#pragma unroll 4
    for (int j = 0; j < 16; j++) {
      float w = twl[tb2][q][j];
      const float* vr = vball + (size_t)txl[tb2][q][j] * 64;
      float4 v0 = *(const float4*)vr;
      float4 v1 = *(const float4*)(vr + 4);
      acc[0] += w * v0.x; acc[1] += w * v0.y;
      acc[2] += w * v0.z; acc[3] += w * v0.w;
      acc[4] += w * v1.x; acc[5] += w * v1.y;
      acc[6] += w * v1.z; acc[7] += w * v1.w;
    }
    int s = q02 + q;
    int M = b * 2048 + s;
    int k = hh * 64 + d0;
    size_t aoff = (size_t)(M >> 4) * 8192 + (size_t)(k >> 5) * 512 +
                  ((((k & 31) >> 3) * 16 + (M & 15)) << 3);
    bf16x8 v;
#pragma unroll
    for (int u = 0; u < 8; u++) v[u] = f2bf(0.5f * acc[u]);
    *(bf16x8*)(spA + aoff) = v;
  }
}

// ---------------------------------------------------------------------------
// gemm_wo + LayerNorm fused. A = ctxlA + spA (both pre-scaled bf16 halves)
// combined on load. Residual from row-major hbf.
// ---------------------------------------------------------------------------
__global__ __launch_bounds__(512, 2) void gemm_wo_ln(
    const short* __restrict__ ctxlA, const short* __restrict__ spA,
    const short* __restrict__ Wbf, const float* __restrict__ bo,
    const short* __restrict__ hbf, const float* __restrict__ g,
    const float* __restrict__ bb, float* __restrict__ outp) {
  int blk = blockIdx.x;                 // 256 blocks, 16 rows each
  int m0 = blk * 16;
  int tid = threadIdx.x;
  int wvv = tid >> 6, lane = tid & 63;
  int quad = lane >> 4, l16 = lane & 15;
  int n0 = wvv * 64;

  __shared__ float rowbuf[16][516];
  __shared__ float mus[16], invs[16];

  const short* lA = ctxlA + (size_t)blk * 8192 + lane * 8;
  const short* sA = spA + (size_t)blk * 8192 + lane * 8;
  const short* bp = Wbf + (size_t)wvv * 32768 + lane * 8;

  auto loadA = [&](int koff) -> bf16x8 {
    bf16x8 l = *(const bf16x8*)(lA + koff);
    bf16x8 s = *(const bf16x8*)(sA + koff);
    bf16x8 v;
#pragma unroll
    for (int e = 0; e < 8; e++) v[e] = f2bf(bf2f(l[e]) + bf2f(s[e]));
    return v;
  };

  f32x4 acc[4] = {};
  bf16x8 cA = loadA(0);
  bf16x8 cB0 = *(const bf16x8*)(bp + 0 * 512);
  bf16x8 cB1 = *(const bf16x8*)(bp + 1 * 512);
  bf16x8 cB2 = *(const bf16x8*)(bp + 2 * 512);
  bf16x8 cB3 = *(const bf16x8*)(bp + 3 * 512);
#pragma unroll 2
  for (int ks = 0; ks < 16; ks++) {
    int kn = (ks + 1 < 16 ? ks + 1 : 15);
    bf16x8 nA = loadA(kn * 512);
    bf16x8 nB0 = *(const bf16x8*)(bp + kn * 2048 + 0 * 512);
    bf16x8 nB1 = *(const bf16x8*)(bp + kn * 2048 + 1 * 512);
    bf16x8 nB2 = *(const bf16x8*)(bp + kn * 2048 + 2 * 512);
    bf16x8 nB3 = *(const bf16x8*)(bp + kn * 2048 + 3 * 512);
    acc[0] = __builtin_amdgcn_mfma_f32_16x16x32_bf16(cA, cB0, acc[0], 0, 0, 0);
    acc[1] = __builtin_amdgcn_mfma_f32_16x16x32_bf16(cA, cB1, acc[1], 0, 0, 0);
    acc[2] = __builtin_amdgcn_mfma_f32_16x16x32_bf16(cA, cB2, acc[2], 0, 0, 0);
    acc[3] = __builtin_amdgcn_mfma_f32_16x16x32_bf16(cA, cB3, acc[3], 0, 0, 0);
    cA = nA;
    cB0 = nB0; cB1 = nB1; cB2 = nB2; cB3 = nB3;
  }
#pragma unroll
  for (int r = 0; r < 4; r++) {
    int rr = quad * 4 + r;
    int m = m0 + rr;
#pragma unroll
    for (int t = 0; t < 4; t++) {
      int n = n0 + t * 16 + l16;
      rowbuf[rr][n] = acc[t][r] + bo[n] + bf2f(hbf[(size_t)m * 512 + n]);
    }
  }
  __syncthreads();
  {
    int row = tid >> 5, seg = tid & 31;
    float s = 0.f, s2 = 0.f;
#pragma unroll
    for (int u = 0; u < 16; u++) {
      float v = rowbuf[row][seg * 16 + u];
      s += v;
      s2 += v * v;
    }
#pragma unroll
    for (int off = 1; off < 32; off <<= 1) {
      s += __shfl_xor(s, off);
      s2 += __shfl_xor(s2, off);
    }
    if (seg == 0) {
      float mu = s * (1.f / 512.f);
      float var = s2 * (1.f / 512.f) - mu * mu;
      mus[row] = mu;
      invs[row] = rsqrtf(var + 1e-5f);
    }
  }
  __syncthreads();
  {
    int row = tid >> 5, seg = tid & 31;
    float mu = mus[row], inv = invs[row];
    float* orow = outp + (size_t)(m0 + row) * 512 + seg * 16;
#pragma unroll
    for (int u = 0; u < 16; u += 4) {
      int c = seg * 16 + u;
      float4 o;
      o.x = (rowbuf[row][c + 0] - mu) * inv * g[c + 0] + bb[c + 0];
      o.y = (rowbuf[row][c + 1] - mu) * inv * g[c + 1] + bb[c + 1];
      o.z = (rowbuf[row][c + 2] - mu) * inv * g[c + 2] + bb[c + 2];
      o.w = (rowbuf[row][c + 3] - mu) * inv * g[c + 3] + bb[c + 3];
      *(float4*)(orow + u) = o;
    }
  }
}

// ---------------------------------------------------------------------------
extern "C" void kernel_launch(void* const* d_in, const int* in_sizes, int n_in,
                              void* d_out, int out_size, void* d_ws,
                              size_t ws_size, hipStream_t stream) {
  const float* x   = (const float*)d_in[0];
  const float* w1  = (const float*)d_in[1];
  const float* b1  = (const float*)d_in[2];
  const float* w2  = (const float*)d_in[3];
  const float* b2  = (const float*)d_in[4];
  const float* w3  = (const float*)d_in[5];
  const float* b3  = (const float*)d_in[6];
  const float* Wq  = (const float*)d_in[7];
  const float* bq  = (const float*)d_in[8];
  const float* Wk  = (const float*)d_in[9];
  const float* bk  = (const float*)d_in[10];
  const float* Wv  = (const float*)d_in[11];
  const float* bv  = (const float*)d_in[12];
  const float* Wkp = (const float*)d_in[13];
  const float* bkp = (const float*)d_in[14];
  const float* Wvp = (const float*)d_in[15];
  const float* bvp = (const float*)d_in[16];
  const float* Wo  = (const float*)d_in[17];
  const float* bo  = (const float*)d_in[18];
  const float* lng = (const float*)d_in[19];
  const float* lnb = (const float*)d_in[20];

  float* p = (float*)d_ws;
  short* Wallbf = (short*)p;  p += 786432;
  float* ball   = p;          p += 2048;
  short* Wobf   = (short*)p;  p += 262144;
  short* Wkpbf  = (short*)p;  p += 4096;
  short* W2bf   = (short*)p;  p += 4096;
  float* cvec   = p;          p += 64;
  short* xbfp   = (short*)p;  p += 262912;
  short* Wcbf   = (short*)p;  p += 229376;
  float* bcat   = p;          p += 512;
  short* hbf    = (short*)p;  p += 1048576;
  short* hAf    = (short*)p;  p += 1048576;
  short* Qh     = (short*)p;  p += 1048576;
  short* Kh     = (short*)p;  p += 1048576;
  short* Vh     = (short*)p;  p += 1048576;
  short* Kfrag  = (short*)p;  p += 1048576;
  float* Vpp    = p;          p += 2097152;
  short* ctxlA  = (short*)p;  p += 1048576;
  short* spA    = (short*)p;  p += 1048576;
  float* outF   = (float*)d_out;

  prep_kernel<<<128, 256, 0, stream>>>(x, w1, b1, w2, b2, w3, b3, bq, bk, bv,
                                       Wkp, Wvp, bvp, ball, Wkpbf, W2bf, cvec,
                                       xbfp, Wcbf, bcat);
  gemm_conv_fused<<<768, 256, 0, stream>>>(xbfp, Wcbf, bcat, hbf, hAf, Wq, Wk,
                                           Wv, Wo, Wallbf, Wobf);
  {
    dim3 g(32, 24);
    gemm_qkv<<<g, 256, 0, stream>>>(hAf, Wallbf, ball, Qh, Kh, Vh);
  }
  kpvp_kernel<<<256, 256, 0, stream>>>(Kh, Vh, Wkpbf, bkp, W2bf, cvec, Kfrag,
                                       Vpp);
  global_local_kernel<<<1536, 256, 0, stream>>>(Qh, Kfrag, Vpp, Kh, Vh, spA,
                                                ctxlA);
  gemm_wo_ln<<<256, 512, 0, stream>>>(ctxlA, spA, Wobf, bo, hbf, lng, lnb,
                                      outF);
}

// Round 18
// 210.549 us; speedup vs baseline: 1.0132x; 1.0132x over previous
//
#include <hip/hip_runtime.h>
#include <hip/hip_bf16.h>

#define BB 2
#define SS 2048
#define INC 64
#define HIDN 512
#define NHH 8
#define HDD 64
#define SP 2054   // padded seq rows per batch (3 zero + 2048 + 3 zero)

typedef __attribute__((ext_vector_type(8))) short bf16x8;
typedef __attribute__((ext_vector_type(4))) float f32x4;

__device__ __forceinline__ short f2bf(float f) {
  union { __hip_bfloat16 h; short s; } u;
  u.h = __float2bfloat16(f);
  return u.s;
}
__device__ __forceinline__ float bf2f(short s) {
  return __uint_as_float(((unsigned)(unsigned short)s) << 16);
}

// Fragment layouts:
//  B-operand of [N][K]: (n>>6)*(K/32*2048) + (k>>5)*2048 + ((n&63)>>4)*512
//                       + (((k&31)>>3)*16+(n&15))*8 + (k&7)
//  A-operand of [M][K=512]: (m>>4)*8192 + (k>>5)*512
//                       + (((k&31)>>3)*16+(m&15))*8 + (k&7)

// ---------------------------------------------------------------------------
// prep (slim): conv-critical packing + small tensors. The heavy
// Wall/Wo frag-packing moved into the gemm_conv launch (overlapped).
// ---------------------------------------------------------------------------
__global__ __launch_bounds__(256) void prep_kernel(
    const float* __restrict__ x, const float* __restrict__ w1,
    const float* __restrict__ b1, const float* __restrict__ w2,
    const float* __restrict__ b2, const float* __restrict__ w3,
    const float* __restrict__ b3, const float* __restrict__ bq,
    const float* __restrict__ bk_, const float* __restrict__ bv_,
    const float* __restrict__ Wkp, const float* __restrict__ Wvp,
    const float* __restrict__ bvp, float* __restrict__ ball,
    short* __restrict__ Wkpbf, short* __restrict__ W2bf,
    float* __restrict__ cvec, short* __restrict__ xbfp,
    short* __restrict__ Wcbf, float* __restrict__ bcat) {
  int i0 = blockIdx.x * 256 + threadIdx.x;
  int stride = gridDim.x * 256;
  for (int g = i0; g < BB * SP * 8; g += stride) {
    int row = g >> 3, c0 = (g & 7) << 3;
    int b = row / SP, pr = row - b * SP;
    int sg = pr - 3;
    bf16x8 v;
    if (sg >= 0 && sg < SS) {
      const float* src = x + ((size_t)(b * SS + sg) << 6) + c0;
      float4 f0 = *(const float4*)src;
      float4 f1 = *(const float4*)(src + 4);
      v[0] = f2bf(f0.x); v[1] = f2bf(f0.y); v[2] = f2bf(f0.z); v[3] = f2bf(f0.w);
      v[4] = f2bf(f1.x); v[5] = f2bf(f1.y); v[6] = f2bf(f1.z); v[7] = f2bf(f1.w);
    } else {
#pragma unroll
      for (int e = 0; e < 8; e++) v[e] = 0;
    }
    *(bf16x8*)(xbfp + ((size_t)row << 6) + c0) = v;
  }
  for (int g = i0; g < 28672; g += stride) {
    int c = g / 56;
    int rem = g - c * 56;
    int k = rem << 3;
    int t = k >> 6;
    int ci0 = k & 63;
    bf16x8 v;
#pragma unroll
    for (int e = 0; e < 8; e++) {
      int ci = ci0 + e;
      float val = 0.f;
      if (c < 171) {
        int kk = t - 2;
        if (kk >= 0 && kk < 3) val = w1[(c * 64 + ci) * 3 + kk];
      } else if (c < 342) {
        int kk = t - 1;
        if (kk >= 0 && kk < 5) val = w2[((c - 171) * 64 + ci) * 5 + kk];
      } else {
        val = w3[((c - 342) * 64 + ci) * 7 + t];
      }
      v[e] = f2bf(val);
    }
    size_t off = (size_t)(c >> 6) * 28672 + (size_t)(k >> 5) * 2048 +
                 (size_t)((c & 63) >> 4) * 512 +
                 ((((k & 31) >> 3) * 16 + (c & 15)) << 3);
    *(bf16x8*)(Wcbf + off) = v;
  }
  for (int idx = i0; idx < 4096; idx += stride) {
    Wkpbf[idx] = f2bf(Wkp[idx]);
    int j = idx >> 6, d = idx & 63;
    float s = 0.f;
#pragma unroll 8
    for (int i = 0; i < 64; i++) s += Wvp[j * 64 + i] * Wvp[i * 64 + d];
    W2bf[idx] = f2bf(s);
  }
  if (i0 < 1536) {
    float v;
    if (i0 < 512)       v = bq[i0];
    else if (i0 < 1024) v = bk_[i0 - 512];
    else                v = bv_[i0 - 1024];
    ball[i0] = v;
  }
  if (i0 < 512) {
    float v;
    if (i0 < 171)      v = b1[i0];
    else if (i0 < 342) v = b2[i0 - 171];
    else               v = b3[i0 - 342];
    bcat[i0] = v;
  }
  if (i0 < 64) {
    float s = bvp[i0];
#pragma unroll 8
    for (int i = 0; i < 64; i++) s += bvp[i] * Wvp[i0 * 64 + i];
    cvec[i0] = s;
  }
}

// ---------------------------------------------------------------------------
// conv GEMM + Wall/Wo frag-packing fused. blocks [0,256): conv GEMM
// (dual-write h). blocks [256,768): Wall (98304 groups) + Wo (32768 groups)
// frag-pack — consumed two launches later, overlapped behind conv's MFMA.
// ---------------------------------------------------------------------------
__global__ __launch_bounds__(256, 4) void gemm_conv_fused(
    const short* __restrict__ xbfp, const short* __restrict__ Wcbf,
    const float* __restrict__ bcat, short* __restrict__ hbf,
    short* __restrict__ hAf, const float* __restrict__ Wq,
    const float* __restrict__ Wk_, const float* __restrict__ Wv_,
    const float* __restrict__ Wo, short* __restrict__ Wallbf,
    short* __restrict__ Wobf) {
  int blk = blockIdx.x;
  int tid = threadIdx.x;
  if (blk >= 256) {
    int i0 = (blk - 256) * 256 + tid;   // 0..131071, one group each
    if (i0 < 98304) {
      int n = i0 >> 6;
      int k = (i0 & 63) << 3;
      const float* src;
      if (n < 512)       src = Wq  + (size_t)n * 512 + k;
      else if (n < 1024) src = Wk_ + (size_t)(n - 512) * 512 + k;
      else               src = Wv_ + (size_t)(n - 1024) * 512 + k;
      float4 f0 = *(const float4*)src;
      float4 f1 = *(const float4*)(src + 4);
      bf16x8 v;
      v[0] = f2bf(f0.x); v[1] = f2bf(f0.y); v[2] = f2bf(f0.z); v[3] = f2bf(f0.w);
      v[4] = f2bf(f1.x); v[5] = f2bf(f1.y); v[6] = f2bf(f1.z); v[7] = f2bf(f1.w);
      size_t off = (size_t)(n >> 6) * 32768 + (size_t)(k >> 5) * 2048 +
                   (size_t)((n & 63) >> 4) * 512 +
                   ((((k & 31) >> 3) * 16 + (n & 15)) << 3);
      *(bf16x8*)(Wallbf + off) = v;
    } else {
      int g = i0 - 98304;
      int n = g >> 6;
      int k = (g & 63) << 3;
      const float* src = Wo + (size_t)n * 512 + k;
      float4 f0 = *(const float4*)src;
      float4 f1 = *(const float4*)(src + 4);
      bf16x8 v;
      v[0] = f2bf(f0.x); v[1] = f2bf(f0.y); v[2] = f2bf(f0.z); v[3] = f2bf(f0.w);
      v[4] = f2bf(f1.x); v[5] = f2bf(f1.y); v[6] = f2bf(f1.z); v[7] = f2bf(f1.w);
      size_t off = (size_t)(n >> 6) * 32768 + (size_t)(k >> 5) * 2048 +
                   (size_t)((n & 63) >> 4) * 512 +
                   ((((k & 31) >> 3) * 16 + (n & 15)) << 3);
      *(bf16x8*)(Wobf + off) = v;
    }
    return;
  }
  int m0 = (blk >> 3) * 128;
  int n0 = (blk & 7) * 64;
  int wvv = tid >> 6, lane = tid & 63;
  int quad = lane >> 4, l16 = lane & 15;
  int mw = m0 + wvv * 32;
  int r0 = mw + l16, r1 = r0 + 16;
  int b0 = r0 >> 11, s0 = r0 & 2047;
  int b1 = r1 >> 11, s1 = r1 & 2047;
  const short* ap0 = xbfp + (size_t)(b0 * SP + s0) * 64 + quad * 8;
  const short* ap1 = xbfp + (size_t)(b1 * SP + s1) * 64 + quad * 8;
  const short* bp = Wcbf + (size_t)(n0 >> 6) * 28672 + lane * 8;
  f32x4 acc[2][4] = {};
  bf16x8 cA0 = *(const bf16x8*)ap0;
  bf16x8 cA1 = *(const bf16x8*)ap1;
  bf16x8 cB0 = *(const bf16x8*)(bp + 0 * 512);
  bf16x8 cB1 = *(const bf16x8*)(bp + 1 * 512);
  bf16x8 cB2 = *(const bf16x8*)(bp + 2 * 512);
  bf16x8 cB3 = *(const bf16x8*)(bp + 3 * 512);
#pragma unroll 2
  for (int ks = 0; ks < 14; ks++) {
    int kn = (ks + 1 < 14 ? ks + 1 : 13);
    int offa = kn * 32;
    int offb = kn * 2048;
    bf16x8 nA0 = *(const bf16x8*)(ap0 + offa);
    bf16x8 nA1 = *(const bf16x8*)(ap1 + offa);
    bf16x8 nB0 = *(const bf16x8*)(bp + offb + 0 * 512);
    bf16x8 nB1 = *(const bf16x8*)(bp + offb + 1 * 512);
    bf16x8 nB2 = *(const bf16x8*)(bp + offb + 2 * 512);
    bf16x8 nB3 = *(const bf16x8*)(bp + offb + 3 * 512);
    acc[0][0] = __builtin_amdgcn_mfma_f32_16x16x32_bf16(cA0, cB0, acc[0][0], 0, 0, 0);
    acc[1][0] = __builtin_amdgcn_mfma_f32_16x16x32_bf16(cA1, cB0, acc[1][0], 0, 0, 0);
    acc[0][1] = __builtin_amdgcn_mfma_f32_16x16x32_bf16(cA0, cB1, acc[0][1], 0, 0, 0);
    acc[1][1] = __builtin_amdgcn_mfma_f32_16x16x32_bf16(cA1, cB1, acc[1][1], 0, 0, 0);
    acc[0][2] = __builtin_amdgcn_mfma_f32_16x16x32_bf16(cA0, cB2, acc[0][2], 0, 0, 0);
    acc[1][2] = __builtin_amdgcn_mfma_f32_16x16x32_bf16(cA1, cB2, acc[1][2], 0, 0, 0);
    acc[0][3] = __builtin_amdgcn_mfma_f32_16x16x32_bf16(cA0, cB3, acc[0][3], 0, 0, 0);
    acc[1][3] = __builtin_amdgcn_mfma_f32_16x16x32_bf16(cA1, cB3, acc[1][3], 0, 0, 0);
    cA0 = nA0; cA1 = nA1;
    cB0 = nB0; cB1 = nB1; cB2 = nB2; cB3 = nB3;
  }
#pragma unroll
  for (int mt = 0; mt < 2; mt++) {
#pragma unroll
    for (int r = 0; r < 4; r++) {
      int m = mw + mt * 16 + quad * 4 + r;
      size_t abase = (size_t)(m >> 4) * 8192;
      int m15 = m & 15;
#pragma unroll
      for (int t = 0; t < 4; t++) {
        int n = n0 + t * 16 + l16;
        float v = fmaxf(acc[mt][t][r] + bcat[n], 0.f);
        short val = f2bf(v);
        hbf[(size_t)m * 512 + n] = val;
        hAf[abase + (size_t)(n >> 5) * 512 +
            ((((n & 31) >> 3) * 16 + m15) << 3) + (n & 7)] = val;
      }
    }
  }
}

// ---------------------------------------------------------------------------
// MFMA QKV gemm. A from frag-packed hAf; B frag-packed.
// ---------------------------------------------------------------------------
__global__ __launch_bounds__(256, 4) void gemm_qkv(
    const short* __restrict__ hAf, const short* __restrict__ Wbf,
    const float* __restrict__ bias, short* __restrict__ Qh,
    short* __restrict__ Kh, short* __restrict__ Vh) {
  int m0 = blockIdx.x * 128;
  int n0 = blockIdx.y * 64;
  int tid = threadIdx.x;
  int wvv = tid >> 6, lane = tid & 63;
  int quad = lane >> 4, l16 = lane & 15;
  int mw = m0 + wvv * 32;
  const short* ap0 = hAf + (size_t)(mw >> 4) * 8192 + lane * 8;
  const short* ap1 = ap0 + 8192;
  const short* bp = Wbf + (size_t)(n0 >> 6) * 32768 + lane * 8;
  f32x4 acc[2][4] = {};
  bf16x8 cA0 = *(const bf16x8*)ap0;
  bf16x8 cA1 = *(const bf16x8*)ap1;
  bf16x8 cB0 = *(const bf16x8*)(bp + 0 * 512);
  bf16x8 cB1 = *(const bf16x8*)(bp + 1 * 512);
  bf16x8 cB2 = *(const bf16x8*)(bp + 2 * 512);
  bf16x8 cB3 = *(const bf16x8*)(bp + 3 * 512);
#pragma unroll 2
  for (int ks = 0; ks < 16; ks++) {
    int kn = (ks + 1 < 16 ? ks + 1 : 15);
    int offab = kn * 512;
    int offb = kn * 2048;
    bf16x8 nA0 = *(const bf16x8*)(ap0 + offab);
    bf16x8 nA1 = *(const bf16x8*)(ap1 + offab);
    bf16x8 nB0 = *(const bf16x8*)(bp + offb + 0 * 512);
    bf16x8 nB1 = *(const bf16x8*)(bp + offb + 1 * 512);
    bf16x8 nB2 = *(const bf16x8*)(bp + offb + 2 * 512);
    bf16x8 nB3 = *(const bf16x8*)(bp + offb + 3 * 512);
    acc[0][0] = __builtin_amdgcn_mfma_f32_16x16x32_bf16(cA0, cB0, acc[0][0], 0, 0, 0);
    acc[1][0] = __builtin_amdgcn_mfma_f32_16x16x32_bf16(cA1, cB0, acc[1][0], 0, 0, 0);
    acc[0][1] = __builtin_amdgcn_mfma_f32_16x16x32_bf16(cA0, cB1, acc[0][1], 0, 0, 0);
    acc[1][1] = __builtin_amdgcn_mfma_f32_16x16x32_bf16(cA1, cB1, acc[1][1], 0, 0, 0);
    acc[0][2] = __builtin_amdgcn_mfma_f32_16x16x32_bf16(cA0, cB2, acc[0][2], 0, 0, 0);
    acc[1][2] = __builtin_amdgcn_mfma_f32_16x16x32_bf16(cA1, cB2, acc[1][2], 0, 0, 0);
    acc[0][3] = __builtin_amdgcn_mfma_f32_16x16x32_bf16(cA0, cB3, acc[0][3], 0, 0, 0);
    acc[1][3] = __builtin_amdgcn_mfma_f32_16x16x32_bf16(cA1, cB3, acc[1][3], 0, 0, 0);
    cA0 = nA0; cA1 = nA1;
    cB0 = nB0; cB1 = nB1; cB2 = nB2; cB3 = nB3;
  }
  int which = n0 >> 9;
  int head = (n0 >> 6) & 7;
  short* dst = which == 0 ? Qh : (which == 1 ? Kh : Vh);
  float scale = which == 0 ? 0.125f : 1.0f;
#pragma unroll
  for (int mt = 0; mt < 2; mt++) {
#pragma unroll
    for (int r = 0; r < 4; r++) {
      int m = mw + mt * 16 + quad * 4 + r;
      int bb = m >> 11, s = m & 2047;
      size_t rowoff = ((size_t)(bb * 8 + head) * 2048 + s) * 64;
#pragma unroll
      for (int t = 0; t < 4; t++) {
        int hd = t * 16 + l16;
        float v = acc[mt][t][r] + bias[n0 + hd];
        dst[rowoff + hd] = f2bf(v * scale);
      }
    }
  }
}

// ---------------------------------------------------------------------------
// kpvp + local_attn fused (independent siblings, one launch).
// blocks [0,256): kpvp — Kfrag (frag-packed) + Vpp.
// blocks [256,768): local windowed attention (one wave / 16-query tile).
// ---------------------------------------------------------------------------
__global__ __launch_bounds__(256, 4) void kpvp_local_kernel(
    const short* __restrict__ Kh, const short* __restrict__ Vh,
    const short* __restrict__ Wkpbf, const float* __restrict__ bkp,
    const short* __restrict__ W2bf, const float* __restrict__ cvec,
    short* __restrict__ Kfrag, float* __restrict__ Vpp,
    const short* __restrict__ Qh, float* __restrict__ ctxl) {
  int tid = threadIdx.x;
  __shared__ float Sloc[4][2][16][17];
  __shared__ float wloc[4][16][8];
  if (blockIdx.x < 256) {
    int m0 = blockIdx.x * 128;
    int wvv = tid >> 6, lane = tid & 63;
    int quad = lane >> 4, l16 = lane & 15;
    int mw = m0 + wvv * 32;
    {
      const short* ap0 = Kh + (size_t)(mw + l16) * 64 + quad * 8;
      const short* ap1 = ap0 + 16 * 64;
      const short* bp = Wkpbf + l16 * 64 + quad * 8;
      bf16x8 A00 = *(const bf16x8*)ap0, A01 = *(const bf16x8*)(ap0 + 32);
      bf16x8 A10 = *(const bf16x8*)ap1, A11 = *(const bf16x8*)(ap1 + 32);
      f32x4 acc[2][4] = {};
#pragma unroll
      for (int t = 0; t < 4; t++) {
        bf16x8 B0 = *(const bf16x8*)(bp + t * 16 * 64);
        bf16x8 B1 = *(const bf16x8*)(bp + t * 16 * 64 + 32);
        acc[0][t] = __builtin_amdgcn_mfma_f32_16x16x32_bf16(A00, B0, acc[0][t], 0, 0, 0);
        acc[0][t] = __builtin_amdgcn_mfma_f32_16x16x32_bf16(A01, B1, acc[0][t], 0, 0, 0);
        acc[1][t] = __builtin_amdgcn_mfma_f32_16x16x32_bf16(A10, B0, acc[1][t], 0, 0, 0);
        acc[1][t] = __builtin_amdgcn_mfma_f32_16x16x32_bf16(A11, B1, acc[1][t], 0, 0, 0);
      }
#pragma unroll
      for (int mt = 0; mt < 2; mt++)
#pragma unroll
        for (int r = 0; r < 4; r++) {
          int m = mw + mt * 16 + quad * 4 + r;
          int m15 = m & 15;
          size_t gbase = (size_t)(m >> 4) * 1024;
#pragma unroll
          for (int t = 0; t < 4; t++) {
            int n = t * 16 + l16;
            short val = f2bf(acc[mt][t][r] + bkp[n]);
            Kfrag[gbase + (size_t)(n >> 5) * 512 +
                  ((((n & 31) >> 3) * 16 + m15) << 3) + (n & 7)] = val;
          }
        }
    }
    {
      const short* ap0 = Vh + (size_t)(mw + l16) * 64 + quad * 8;
      const short* ap1 = ap0 + 16 * 64;
      const short* bp = W2bf + l16 * 64 + quad * 8;
      bf16x8 A00 = *(const bf16x8*)ap0, A01 = *(const bf16x8*)(ap0 + 32);
      bf16x8 A10 = *(const bf16x8*)ap1, A11 = *(const bf16x8*)(ap1 + 32);
      f32x4 acc[2][4] = {};
#pragma unroll
      for (int t = 0; t < 4; t++) {
        bf16x8 B0 = *(const bf16x8*)(bp + t * 16 * 64);
        bf16x8 B1 = *(const bf16x8*)(bp + t * 16 * 64 + 32);
        acc[0][t] = __builtin_amdgcn_mfma_f32_16x16x32_bf16(A00, B0, acc[0][t], 0, 0, 0);
        acc[0][t] = __builtin_amdgcn_mfma_f32_16x16x32_bf16(A01, B1, acc[0][t], 0, 0, 0);
        acc[1][t] = __builtin_amdgcn_mfma_f32_16x16x32_bf16(A10, B0, acc[1][t], 0, 0, 0);
        acc[1][t] = __builtin_amdgcn_mfma_f32_16x16x32_bf16(A11, B1, acc[1][t], 0, 0, 0);
      }
#pragma unroll
      for (int mt = 0; mt < 2; mt++)
#pragma unroll
        for (int r = 0; r < 4; r++) {
          int m = mw + mt * 16 + quad * 4 + r;
#pragma unroll
          for (int t = 0; t < 4; t++) {
            int n = t * 16 + l16;
            Vpp[(size_t)m * 64 + n] = acc[mt][t][r] + cvec[n];
          }
        }
    }
    return;
  }
  // ---- local windowed attention ----
  int wv = tid >> 6;
  int tile = (blockIdx.x - 256) * 4 + wv;   // 0..2047
  int bh = tile >> 7;
  int q0 = (tile & 127) * 16;
  int lane = tid & 63;
  int quad = lane >> 4, l16 = lane & 15;

  const short* qbase = Qh + (size_t)(bh * 2048 + q0 + l16) * 64 + quad * 8;
  bf16x8 a0 = *(const bf16x8*)qbase;
  bf16x8 a1 = *(const bf16x8*)(qbase + 32);

  int k0a = min(max(q0 - 2 + l16, 0), 2047);
  int k1a = min(q0 + 6 + l16, 2047);
  const short* kb0 = Kh + (size_t)(bh * 2048 + k0a) * 64 + quad * 8;
  const short* kb1 = Kh + (size_t)(bh * 2048 + k1a) * 64 + quad * 8;
  bf16x8 B00 = *(const bf16x8*)kb0;
  bf16x8 B01 = *(const bf16x8*)(kb0 + 32);
  bf16x8 B10 = *(const bf16x8*)kb1;
  bf16x8 B11 = *(const bf16x8*)(kb1 + 32);
  f32x4 C0 = {0.f, 0.f, 0.f, 0.f};
  f32x4 C1 = {0.f, 0.f, 0.f, 0.f};
  C0 = __builtin_amdgcn_mfma_f32_16x16x32_bf16(a0, B00, C0, 0, 0, 0);
  C0 = __builtin_amdgcn_mfma_f32_16x16x32_bf16(a1, B01, C0, 0, 0, 0);
  C1 = __builtin_amdgcn_mfma_f32_16x16x32_bf16(a0, B10, C1, 0, 0, 0);
  C1 = __builtin_amdgcn_mfma_f32_16x16x32_bf16(a1, B11, C1, 0, 0, 0);
#pragma unroll
  for (int r = 0; r < 4; r++) {
    Sloc[wv][0][quad * 4 + r][l16] = C0[r];
    Sloc[wv][1][quad * 4 + r][l16] = C1[r];
  }
  __builtin_amdgcn_wave_barrier();
  if (lane < 16) {
    int q = lane;
    float sc[5];
    bool ok[5];
#pragma unroll
    for (int j = 0; j < 5; j++) {
      int offq = q + j - 2;
      int sg = q0 + offq;
      ok[j] = (sg >= 0 && sg < SS);
      int t = offq <= 13 ? 0 : 1;
      int col = t ? offq - 6 : offq + 2;
      sc[j] = ok[j] ? Sloc[wv][t][q][col] : -3.0e38f;
    }
    float m = -3.0e38f;
#pragma unroll
    for (int j = 0; j < 5; j++) m = fmaxf(m, sc[j]);
    float e[5], l = 0.f;
#pragma unroll
    for (int j = 0; j < 5; j++) {
      e[j] = ok[j] ? __expf(sc[j] - m) : 0.f;
      l += e[j];
    }
    float inv = 1.f / l;
#pragma unroll
    for (int j = 0; j < 5; j++) wloc[wv][q][j] = e[j] * inv;
  }
  __builtin_amdgcn_wave_barrier();
  {
    int q = lane >> 2, jb = (lane & 3) * 16;
    int s = q0 + q;
    float acc[16] = {};
#pragma unroll
    for (int j = 0; j < 5; j++) {
      int sg = s + j - 2;
      if (sg >= 0 && sg < SS) {
        float w = wloc[wv][q][j];
        const short* vr = Vh + (size_t)(bh * 2048 + sg) * 64 + jb;
#pragma unroll
        for (int u = 0; u < 16; u += 4) {
          short4 v4 = *(const short4*)(vr + u);
          acc[u + 0] += w * bf2f(v4.x);
          acc[u + 1] += w * bf2f(v4.y);
          acc[u + 2] += w * bf2f(v4.z);
          acc[u + 3] += w * bf2f(v4.w);
        }
      }
    }
    float* orow = ctxl + (size_t)(bh * 2048 + s) * 64 + jb;
#pragma unroll
    for (int u = 0; u < 16; u += 4)
      *(float4*)(orow + u) =
          make_float4(acc[u], acc[u + 1], acc[u + 2], acc[u + 3]);
  }
}

// ---------------------------------------------------------------------------
// global sparse attention — v12 core; ctxcb written in A-FRAG order.
// ---------------------------------------------------------------------------
__global__ __launch_bounds__(256, 4) void global_attn(
    const short* __restrict__ Qh, const short* __restrict__ Kfrag,
    const float* __restrict__ Vpp, const float* __restrict__ ctxl,
    short* __restrict__ ctxcb) {
  int tid = threadIdx.x;
  int wv = tid >> 6;
  int lane = tid & 63;
  int quad = lane >> 4, l16 = lane & 15;
  int tb = wv >> 1;
  int half = wv & 1;
  int p = blockIdx.x;
  int bh = (p & 7) * 2 + ((p >> 3) & 1);
  int seg = p >> 4;
  int tile = seg * 2 + tb;
  int q0 = tile * 16;

  __shared__ unsigned swl[4][16][17];
  __shared__ float twl[2][16][17];
  __shared__ int   txl[2][16][17];

  const short* qbase = Qh + (size_t)(bh * 2048 + q0 + l16) * 64 + quad * 8;
  bf16x8 a0 = *(const bf16x8*)qbase;
  bf16x8 a1 = *(const bf16x8*)(qbase + 32);

  const short* kf =
      Kfrag + (size_t)bh * (128 * 1024) + (size_t)half * (64 * 1024) + lane * 8;

  unsigned er[4][8];
#pragma unroll
  for (int a = 0; a < 4; a++)
#pragma unroll
    for (int j = 0; j < 8; j++) er[a][j] = 0u;

  auto insert8 = [&](unsigned (&e)[8], unsigned cand) {
    unsigned n0, n1, n2, n3, n4, n5, n6, n7;
    asm("v_max_u32 %0, %1, %2" : "=v"(n0) : "v"(e[0]), "v"(cand));
    asm("v_med3_u32 %0, %1, %2, %3" : "=v"(n1) : "v"(e[0]), "v"(e[1]), "v"(cand));
    asm("v_med3_u32 %0, %1, %2, %3" : "=v"(n2) : "v"(e[1]), "v"(e[2]), "v"(cand));
    asm("v_med3_u32 %0, %1, %2, %3" : "=v"(n3) : "v"(e[2]), "v"(e[3]), "v"(cand));
    asm("v_med3_u32 %0, %1, %2, %3" : "=v"(n4) : "v"(e[3]), "v"(e[4]), "v"(cand));
    asm("v_med3_u32 %0, %1, %2, %3" : "=v"(n5) : "v"(e[4]), "v"(e[5]), "v"(cand));
    asm("v_med3_u32 %0, %1, %2, %3" : "=v"(n6) : "v"(e[5]), "v"(e[6]), "v"(cand));
    asm("v_med3_u32 %0, %1, %2, %3" : "=v"(n7) : "v"(e[6]), "v"(e[7]), "v"(cand));
    e[0] = n0; e[1] = n1; e[2] = n2; e[3] = n3;
    e[4] = n4; e[5] = n5; e[6] = n6; e[7] = n7;
  };
  auto mkcand = [&](float s, int idxr) -> unsigned {
    unsigned u = __float_as_uint(s);
    u ^= ((unsigned)((int)u >> 31)) | 0x80000000u;
    return (u & 0xFFFFF800u) | (unsigned)idxr;
  };

  int idxb = 2047 - half * 1024 - l16;
#pragma unroll 4
  for (int g = 0; g < 64; g++) {
    bf16x8 B00 = *(const bf16x8*)(kf + g * 1024);
    bf16x8 B01 = *(const bf16x8*)(kf + g * 1024 + 512);
    f32x4 C0 = {0.f, 0.f, 0.f, 0.f};
    C0 = __builtin_amdgcn_mfma_f32_16x16x32_bf16(a0, B00, C0, 0, 0, 0);
    C0 = __builtin_amdgcn_mfma_f32_16x16x32_bf16(a1, B01, C0, 0, 0, 0);
    int idxr = idxb - (g << 4);
    insert8(er[0], mkcand(C0[0], idxr));
    insert8(er[1], mkcand(C0[1], idxr));
    insert8(er[2], mkcand(C0[2], idxr));
    insert8(er[3], mkcand(C0[3], idxr));
  }

  {
    unsigned sw[4] = {0u, 0u, 0u, 0u};
#pragma unroll
    for (int t = 0; t < 16; t++) {
#pragma unroll
      for (int a = 0; a < 4; a++) {
        unsigned w = er[a][0];
#pragma unroll
        for (int mm = 1; mm <= 8; mm <<= 1) {
          unsigned o = (unsigned)__shfl_xor((int)w, mm);
          w = w > o ? w : o;
        }
        bool pop = (er[a][0] == w);
#pragma unroll
        for (int j = 0; j < 7; j++) er[a][j] = pop ? er[a][j + 1] : er[a][j];
        er[a][7] = pop ? 0u : er[a][7];
        if (l16 == t) sw[a] = w;
      }
    }
#pragma unroll
    for (int a = 0; a < 4; a++) swl[wv][quad * 4 + a][l16] = sw[a];
  }
  __syncthreads();

  if (tid < 32) {
    int tb2 = tid >> 4, q = tid & 15;
    const unsigned* A = swl[tb2 * 2][q];
    const unsigned* Bv = swl[tb2 * 2 + 1][q];
    auto decode = [&](unsigned w) -> float {
      unsigned wb = w & 0xFFFFF800u;
      unsigned uu = (w & 0x80000000u) ? (wb ^ 0x80000000u) : ~wb;
      return (w == 0u) ? -1.0e30f : __uint_as_float(uu);
    };
    unsigned h0 = A[0], h1 = Bv[0];
    float mval = decode(h0 > h1 ? h0 : h1);
    float lsum = 0.f;
    float ev[16];
    int ki[16];
#pragma unroll
    for (int i = 0; i < 16; i++) {
      unsigned wa = A[i], wb2 = Bv[15 - i];
      unsigned w = wa > wb2 ? wa : wb2;
      float sv = decode(w);
      float ex = __expf(sv - mval);
      lsum += ex;
      ev[i] = ex;
      ki[i] = 2047 - (int)(w & 0x7FFu);
    }
    float inv = 1.f / lsum;
#pragma unroll
    for (int i = 0; i < 16; i++) {
      twl[tb2][q][i] = ev[i] * inv;
      txl[tb2][q][i] = ki[i];
    }
  }
  __syncthreads();

  {
    int tb2 = tid >> 7;
    int r = tid & 127;
    int q = r >> 3, d0 = (r & 7) * 8;
    int tile2 = seg * 2 + tb2;
    int q02 = tile2 * 16;
    int b = bh >> 3, hh = bh & 7;
    const float* vball = Vpp + (size_t)bh * (2048 * 64) + d0;
    float acc[8];
#pragma unroll
    for (int u = 0; u < 8; u++) acc[u] = 0.f;
#pragma unroll 4
    for (int j = 0; j < 16; j++) {
      float w = twl[tb2][q][j];
      const float* vr = vball + (size_t)txl[tb2][q][j] * 64;
      float4 v0 = *(const float4*)vr;
      float4 v1 = *(const float4*)(vr + 4);
      acc[0] += w * v0.x; acc[1] += w * v0.y;
      acc[2] += w * v0.z; acc[3] += w * v0.w;
      acc[4] += w * v1.x; acc[5] += w * v1.y;
      acc[6] += w * v1.z; acc[7] += w * v1.w;
    }
    int s = q02 + q;
    const float* lrow = ctxl + (size_t)(bh * 2048 + s) * 64 + d0;
    int M = b * 2048 + s;
    int k = hh * 64 + d0;
    size_t aoff = (size_t)(M >> 4) * 8192 + (size_t)(k >> 5) * 512 +
                  ((((k & 31) >> 3) * 16 + (M & 15)) << 3);
    float4 lv0 = *(const float4*)lrow;
    float4 lv1 = *(const float4*)(lrow + 4);
    short4 o0, o1;
    o0.x = f2bf(0.5f * (lv0.x + acc[0]));
    o0.y = f2bf(0.5f * (lv0.y + acc[1]));
    o0.z = f2bf(0.5f * (lv0.z + acc[2]));
    o0.w = f2bf(0.5f * (lv0.w + acc[3]));
    o1.x = f2bf(0.5f * (lv1.x + acc[4]));
    o1.y = f2bf(0.5f * (lv1.y + acc[5]));
    o1.z = f2bf(0.5f * (lv1.z + acc[6]));
    o1.w = f2bf(0.5f * (lv1.w + acc[7]));
    *(short4*)(ctxcb + aoff) = o0;
    *(short4*)(ctxcb + aoff + 4) = o1;
  }
}

// ---------------------------------------------------------------------------
// gemm_wo + LayerNorm fused: block = 16 complete rows x 512 cols,
// 512 threads = 8 waves (one 64-col n-block each). acc+bias+residual ->
// LDS row buffer -> per-row mean/var (shfl over 32-lane groups) -> final
// fp32 LN output.
// ---------------------------------------------------------------------------
__global__ __launch_bounds__(512, 2) void gemm_wo_ln(
    const short* __restrict__ Abf, const short* __restrict__ Wbf,
    const float* __restrict__ bo, const short* __restrict__ hbf,
    const float* __restrict__ g, const float* __restrict__ bb,
    float* __restrict__ outp) {
  int blk = blockIdx.x;                 // 256 blocks, 16 rows each
  int m0 = blk * 16;
  int tid = threadIdx.x;
  int wvv = tid >> 6, lane = tid & 63;
  int quad = lane >> 4, l16 = lane & 15;
  int n0 = wvv * 64;

  __shared__ float rowbuf[16][516];
  __shared__ float mus[16], invs[16];

  const short* ap = Abf + (size_t)blk * 8192 + lane * 8;
  const short* bp = Wbf + (size_t)wvv * 32768 + lane * 8;
  f32x4 acc[4] = {};
  bf16x8 cA = *(const bf16x8*)ap;
  bf16x8 cB0 = *(const bf16x8*)(bp + 0 * 512);
  bf16x8 cB1 = *(const bf16x8*)(bp + 1 * 512);
  bf16x8 cB2 = *(const bf16x8*)(bp + 2 * 512);
  bf16x8 cB3 = *(const bf16x8*)(bp + 3 * 512);
#pragma unroll 2
  for (int ks = 0; ks < 16; ks++) {
    int kn = (ks + 1 < 16 ? ks + 1 : 15);
    bf16x8 nA = *(const bf16x8*)(ap + kn * 512);
    bf16x8 nB0 = *(const bf16x8*)(bp + kn * 2048 + 0 * 512);
    bf16x8 nB1 = *(const bf16x8*)(bp + kn * 2048 + 1 * 512);
    bf16x8 nB2 = *(const bf16x8*)(bp + kn * 2048 + 2 * 512);
    bf16x8 nB3 = *(const bf16x8*)(bp + kn * 2048 + 3 * 512);
    acc[0] = __builtin_amdgcn_mfma_f32_16x16x32_bf16(cA, cB0, acc[0], 0, 0, 0);
    acc[1] = __builtin_amdgcn_mfma_f32_16x16x32_bf16(cA, cB1, acc[1], 0, 0, 0);
    acc[2] = __builtin_amdgcn_mfma_f32_16x16x32_bf16(cA, cB2, acc[2], 0, 0, 0);
    acc[3] = __builtin_amdgcn_mfma_f32_16x16x32_bf16(cA, cB3, acc[3], 0, 0, 0);
    cA = nA;
    cB0 = nB0; cB1 = nB1; cB2 = nB2; cB3 = nB3;
  }
#pragma unroll
  for (int r = 0; r < 4; r++) {
    int rr = quad * 4 + r;
    int m = m0 + rr;
#pragma unroll
    for (int t = 0; t < 4; t++) {
      int n = n0 + t * 16 + l16;
      rowbuf[rr][n] = acc[t][r] + bo[n] + bf2f(hbf[(size_t)m * 512 + n]);
    }
  }
  __syncthreads();
  // Per-row reduction: 32 threads/row (tid>>5 = row), each sums 16 cols.
  {
    int row = tid >> 5, seg = tid & 31;
    float s = 0.f, s2 = 0.f;
#pragma unroll
    for (int u = 0; u < 16; u++) {
      float v = rowbuf[row][seg * 16 + u];
      s += v;
      s2 += v * v;
    }
#pragma unroll
    for (int off = 1; off < 32; off <<= 1) {
      s += __shfl_xor(s, off);
      s2 += __shfl_xor(s2, off);
    }
    if (seg == 0) {
      float mu = s * (1.f / 512.f);
      float var = s2 * (1.f / 512.f) - mu * mu;
      mus[row] = mu;
      invs[row] = rsqrtf(var + 1e-5f);
    }
  }
  __syncthreads();
  {
    int row = tid >> 5, seg = tid & 31;
    float mu = mus[row], inv = invs[row];
    float* orow = outp + (size_t)(m0 + row) * 512 + seg * 16;
#pragma unroll
    for (int u = 0; u < 16; u += 4) {
      int c = seg * 16 + u;
      float4 o;
      o.x = (rowbuf[row][c + 0] - mu) * inv * g[c + 0] + bb[c + 0];
      o.y = (rowbuf[row][c + 1] - mu) * inv * g[c + 1] + bb[c + 1];
      o.z = (rowbuf[row][c + 2] - mu) * inv * g[c + 2] + bb[c + 2];
      o.w = (rowbuf[row][c + 3] - mu) * inv * g[c + 3] + bb[c + 3];
      *(float4*)(orow + u) = o;
    }
  }
}

// ---------------------------------------------------------------------------
extern "C" void kernel_launch(void* const* d_in, const int* in_sizes, int n_in,
                              void* d_out, int out_size, void* d_ws,
                              size_t ws_size, hipStream_t stream) {
  const float* x   = (const float*)d_in[0];
  const float* w1  = (const float*)d_in[1];
  const float* b1  = (const float*)d_in[2];
  const float* w2  = (const float*)d_in[3];
  const float* b2  = (const float*)d_in[4];
  const float* w3  = (const float*)d_in[5];
  const float* b3  = (const float*)d_in[6];
  const float* Wq  = (const float*)d_in[7];
  const float* bq  = (const float*)d_in[8];
  const float* Wk  = (const float*)d_in[9];
  const float* bk  = (const float*)d_in[10];
  const float* Wv  = (const float*)d_in[11];
  const float* bv  = (const float*)d_in[12];
  const float* Wkp = (const float*)d_in[13];
  const float* bkp = (const float*)d_in[14];
  const float* Wvp = (const float*)d_in[15];
  const float* bvp = (const float*)d_in[16];
  const float* Wo  = (const float*)d_in[17];
  const float* bo  = (const float*)d_in[18];
  const float* lng = (const float*)d_in[19];
  const float* lnb = (const float*)d_in[20];

  float* p = (float*)d_ws;
  short* Wallbf = (short*)p;  p += 786432;
  float* ball   = p;          p += 2048;
  short* Wobf   = (short*)p;  p += 262144;
  short* Wkpbf  = (short*)p;  p += 4096;
  short* W2bf   = (short*)p;  p += 4096;
  float* cvec   = p;          p += 64;
  short* xbfp   = (short*)p;  p += 262912;
  short* Wcbf   = (short*)p;  p += 229376;
  float* bcat   = p;          p += 512;
  short* hbf    = (short*)p;  p += 1048576;
  short* hAf    = (short*)p;  p += 1048576;
  short* Qh     = (short*)p;  p += 1048576;
  short* Kh     = (short*)p;  p += 1048576;
  short* Vh     = (short*)p;  p += 1048576;
  short* Kfrag  = (short*)p;  p += 1048576;
  float* Vpp    = p;          p += 2097152;
  float* ctxl   = p;          p += 2097152;
  short* ctxcb  = (short*)p;  p += 1048576;
  float* outF   = (float*)d_out;

  prep_kernel<<<128, 256, 0, stream>>>(x, w1, b1, w2, b2, w3, b3, bq, bk, bv,
                                       Wkp, Wvp, bvp, ball, Wkpbf, W2bf, cvec,
                                       xbfp, Wcbf, bcat);
  gemm_conv_fused<<<768, 256, 0, stream>>>(xbfp, Wcbf, bcat, hbf, hAf, Wq, Wk,
                                           Wv, Wo, Wallbf, Wobf);
  {
    dim3 g(32, 24);
    gemm_qkv<<<g, 256, 0, stream>>>(hAf, Wallbf, ball, Qh, Kh, Vh);
  }
  kpvp_local_kernel<<<768, 256, 0, stream>>>(Kh, Vh, Wkpbf, bkp, W2bf, cvec,
                                             Kfrag, Vpp, Qh, ctxl);
  global_attn<<<1024, 256, 0, stream>>>(Qh, Kfrag, Vpp, ctxl, ctxcb);
  gemm_wo_ln<<<256, 512, 0, stream>>>(ctxcb, Wobf, bo, hbf, lng, lnb, outF);
}